// Round 8
// baseline (229.586 us; speedup 1.0000x reference)
//
#include <hip/hip_runtime.h>
#include <hip/hip_bf16.h>
#include <math.h>

#define L1_     5248
#define LENRRC_ 129
#define TSTART_ 65
#define NWIN_   5120
#define SWZ(m) ((m) + ((m) >> 3))     // stride-8 reads -> stride-9 -> conflict-free

typedef __attribute__((ext_vector_type(8))) short s16x8;   // 8 bf16 lanes (4 VGPRs)
typedef __attribute__((ext_vector_type(4))) float f32x4;   // MFMA accumulator

// split fp32 -> hi bf16 (RNE) + lo bf16 (trunc of residual)
__device__ inline void split1(float x, ushort& h, ushort& l) {
    unsigned xb = __float_as_uint(x);
    unsigned hi = (xb + 0x7fffu + ((xb >> 16) & 1u)) & 0xffff0000u;
    h = (ushort)(hi >> 16);
    l = (ushort)(__float_as_uint(x - __uint_as_float(hi)) >> 16);
}
__device__ inline unsigned pack_pair(float x) {   // hi in high16 | lo in low16
    unsigned xb = __float_as_uint(x);
    unsigned hi = (xb + 0x7fffu + ((xb >> 16) & 1u)) & 0xffff0000u;
    float lof = x - __uint_as_float(hi);
    return hi | (__float_as_uint(lof) >> 16);
}

__device__ inline float wave_sum(float v) {
    #pragma unroll
    for (int m = 32; m > 0; m >>= 1) v += __shfl_xor(v, m, 64);
    return v;
}
__device__ inline float wave_max(float v) {
    #pragma unroll
    for (int m = 32; m > 0; m >>= 1) v = fmaxf(v, __shfl_xor(v, m, 64));
    return v;
}

// ---------- pack A (elementwise): fp32 -> hi/lo bf16 planes ----------
__global__ __launch_bounds__(256) void packA_k(const float* __restrict__ A,
        ushort* __restrict__ Ah, ushort* __restrict__ Al) {
    int i = blockIdx.x * 256 + threadIdx.x;          // x4 floats
    float4 v = ((const float4*)A)[i];
    ushort4 h, l;
    split1(v.x, h.x, l.x); split1(v.y, h.y, l.y);
    split1(v.z, h.z, l.z); split1(v.w, h.w, l.w);
    ((ushort4*)Ah)[i] = h; ((ushort4*)Al)[i] = l;
}

// ---------- pack W (K x N) -> transposed hi/lo planes (N x K) ----------
__global__ __launch_bounds__(256) void packWt_k(const float* __restrict__ W,
        ushort* __restrict__ Th, ushort* __restrict__ Tl, int K, int N) {
    __shared__ unsigned tile[64][65];
    const int n0 = blockIdx.x * 64, k0 = blockIdx.y * 64;
    const int t = threadIdx.x;
    const int cr = t >> 4, cc = (t & 15) * 4;
    #pragma unroll
    for (int i = 0; i < 4; ++i) {
        int kk = i * 16 + cr;
        float4 v = *(const float4*)&W[(size_t)(k0 + kk) * N + n0 + cc];
        tile[kk][cc]     = pack_pair(v.x);
        tile[kk][cc + 1] = pack_pair(v.y);
        tile[kk][cc + 2] = pack_pair(v.z);
        tile[kk][cc + 3] = pack_pair(v.w);
    }
    __syncthreads();
    #pragma unroll
    for (int i = 0; i < 4; ++i) {
        int nn = i * 16 + cr;
        unsigned a = tile[cc][nn], b = tile[cc + 1][nn];
        unsigned c = tile[cc + 2][nn], d = tile[cc + 3][nn];
        ushort4 h, l;
        h.x = (ushort)(a >> 16); h.y = (ushort)(b >> 16);
        h.z = (ushort)(c >> 16); h.w = (ushort)(d >> 16);
        l.x = (ushort)a; l.y = (ushort)b; l.z = (ushort)c; l.w = (ushort)d;
        *(ushort4*)&Th[(size_t)(n0 + nn) * K + k0 + cc] = h;
        *(ushort4*)&Tl[(size_t)(n0 + nn) * K + k0 + cc] = l;
    }
}

// ---------- init z / out with bias ----------
__global__ __launch_bounds__(256) void initz_k(float* z, const float* bias) {
    int i = blockIdx.x * 256 + threadIdx.x;          // 524288 total
    z[i] = bias[i & 511];
}
__global__ __launch_bounds__(256) void initout_k(float* out, const float* bias) {
    int i = blockIdx.x * 256 + threadIdx.x;          // 3145728 total
    out[i] = bias[i & 3071];
}

// ---------- plane GEMM: 128x128x32 tiles, hi/lo bf16 planes, triple MFMA ----------
// C += A @ B^T-planes; atomic accumulate (SK slices collide)
template<int SK>
__global__ __launch_bounds__(256) void gemm_planes_k(
        const ushort* __restrict__ Ah, const ushort* __restrict__ Al,
        const ushort* __restrict__ Bh, const ushort* __restrict__ Bl,
        float* __restrict__ C, int M, int N, int K)
{
    __shared__ ushort lds[4 * 5120];    // 4 planes x 128 rows x 40 (pad) = 40 KB
    const int tid = threadIdx.x;
    const int lane = tid & 63, wave = tid >> 6;
    const int wm = (wave >> 1) * 64, wn = (wave & 1) * 64;
    const int m0 = blockIdx.y * 128, n0 = blockIdx.x * 128;
    const int kch = K / SK, kbeg = blockIdx.z * kch, kend = kbeg + kch;
    const int fm = lane & 15, q = lane >> 4;
    f32x4 acc[4][4] = {};

    const ushort* srcs[4] = {Ah, Al, Bh, Bl};
    for (int kt = kbeg; kt < kend; kt += 32) {
        #pragma unroll
        for (int p = 0; p < 4; ++p) {
            const ushort* src = srcs[p];
            int r0 = (p < 2) ? m0 : n0;
            #pragma unroll
            for (int i = 0; i < 2; ++i) {
                int c = i * 256 + tid;
                int row = c >> 2, k8 = (c & 3) * 8;
                uint4 v = *(const uint4*)&src[(size_t)(r0 + row) * K + kt + k8];
                *(uint4*)&lds[p * 5120 + row * 40 + k8] = v;   // ds_write_b128
            }
        }
        __syncthreads();
        s16x8 ah[4], al[4];
        #pragma unroll
        for (int mf = 0; mf < 4; ++mf) {
            ah[mf] = *(const s16x8*)&lds[0 * 5120 + (wm + mf * 16 + fm) * 40 + q * 8];
            al[mf] = *(const s16x8*)&lds[1 * 5120 + (wm + mf * 16 + fm) * 40 + q * 8];
        }
        #pragma unroll
        for (int nf = 0; nf < 4; ++nf) {
            s16x8 bh = *(const s16x8*)&lds[2 * 5120 + (wn + nf * 16 + fm) * 40 + q * 8];
            s16x8 bl = *(const s16x8*)&lds[3 * 5120 + (wn + nf * 16 + fm) * 40 + q * 8];
            #pragma unroll
            for (int mf = 0; mf < 4; ++mf) {
                acc[mf][nf] = __builtin_amdgcn_mfma_f32_16x16x32_bf16(ah[mf], bh, acc[mf][nf], 0, 0, 0);
                acc[mf][nf] = __builtin_amdgcn_mfma_f32_16x16x32_bf16(ah[mf], bl, acc[mf][nf], 0, 0, 0);
                acc[mf][nf] = __builtin_amdgcn_mfma_f32_16x16x32_bf16(al[mf], bh, acc[mf][nf], 0, 0, 0);
            }
        }
        __syncthreads();
    }

    #pragma unroll
    for (int mf = 0; mf < 4; ++mf)
        #pragma unroll
        for (int nf = 0; nf < 4; ++nf)
            #pragma unroll
            for (int r = 0; r < 4; ++r) {
                int m = m0 + wm + mf * 16 + q * 4 + r;
                int n = n0 + wn + nf * 16 + fm;
                atomicAdd(&C[(size_t)m * N + n], acc[mf][nf][r]);
            }
}

// ---------- megakernel: one block per batch row, whole signal chain in LDS ----------
__global__ __launch_bounds__(256) void mega_k(const float* __restrict__ z,
        const float* __restrict__ rrc, const float* __restrict__ awgn,
        const int* __restrict__ slocp, ushort* __restrict__ y5h, ushort* __restrict__ y5l,
        float* __restrict__ papr, float* __restrict__ out_papr)
{
    __shared__ float  zl[512];
    __shared__ float2 frfi[8][32];
    __shared__ float2 trti[640];
    __shared__ float  hl[132];
    __shared__ float  csl[16], ssl[16];
    __shared__ float2 cs64[64];
    __shared__ float2 gcs[130];
    __shared__ float  dxr[SWZ(L1_ - 1) + 1];
    __shared__ float2 wrli[512];
    __shared__ float  red[4], red2[4];

    const int b = blockIdx.x, tid = threadIdx.x;
    const int lane = tid & 63, wv = tid >> 6;
    const int sloc = *slocp;

    // ---- tables ----
    if (tid < 64) {
        float ang = 0.09817477042468103f * (float)tid;   // 2pi/64
        float s, c; sincosf(ang, &s, &c);
        cs64[tid] = make_float2(c, s);
    }
    if (tid >= 64 && tid < 80) {
        int t = tid - 64;
        float ang = 1.9634954084936207f * (float)t;      // 2pi*5/16
        float s, c; sincosf(ang, &s, &c);
        csl[t] = 1.4142135623730951f * c; ssl[t] = 1.4142135623730951f * s;
    }
    for (int e = tid; e < LENRRC_; e += 256) hl[e] = rrc[e];
    float v0 = z[(size_t)b * 512 + tid];
    float v1 = z[(size_t)b * 512 + tid + 256];
    __syncthreads();

    // ---- gcs: carrier folded into RRC taps ----
    if (tid < LENRRC_) {
        int neg = (16 - (tid & 15)) & 15;                // (-d) & 15
        gcs[tid] = make_float2(hl[tid] * csl[neg], hl[tid] * ssl[neg]);
    }

    // ---- power norm (single pass: S, Q; ddof=1) ----
    {
        float S = wave_sum(v0 + v1);
        float Q = wave_sum(v0 * v0 + v1 * v1);
        if (lane == 0) { red[wv] = S; red2[wv] = Q; }
    }
    __syncthreads();
    {
        float S = red[0] + red[1] + red[2] + red[3];
        float Q = red2[0] + red2[1] + red2[2] + red2[3];
        float mean = S * (1.f / 512.f);
        float var = (Q - S * mean) * (1.f / 511.f);
        float inv = 1.f / (sqrtf(var) + 1e-8f);
        zl[tid] = (v0 - mean) * inv; zl[tid + 256] = (v1 - mean) * inv;
    }
    __syncthreads();

    // ---- P1: DFT32 (+fftshift folded) ----
    {
        int s = tid >> 5, kk = tid & 31;
        int kk2 = (kk + 16) & 31;
        float sr = 0.f, si = 0.f;
        int t2 = 0;
        for (int q = 0; q < 32; ++q) {
            float2 w = cs64[2 * t2];
            float2 c = *(const float2*)&zl[(s * 32 + q) * 2];
            sr += c.x * w.x + c.y * w.y;                 // * e^{-i ang}
            si += c.y * w.x - c.x * w.y;
            t2 = (t2 + kk2) & 31;
        }
        frfi[s][kk] = make_float2(sr * 0.1767766952966369f, si * 0.1767766952966369f);
    }
    __syncthreads();

    // ---- P2: IDFT64 + CP ----
    #pragma unroll
    for (int e0 = 0; e0 < 2; ++e0) {
        int e = e0 * 256 + tid;
        int s = e >> 6, n = e & 63;
        float dr = 0.f, di = 0.f;
        int t = (sloc * n) & 63;
        for (int k = 0; k < 32; ++k) {
            float2 w = cs64[t];
            float2 f = frfi[s][k];
            dr += f.x * w.x - f.y * w.y;                 // * e^{+i ang}
            di += f.y * w.x + f.x * w.y;
            t = (t + n) & 63;
        }
        float2 d2 = make_float2(dr * 0.125f, di * 0.125f);
        int base = s * 80;
        trti[base + 16 + n] = d2;
        if (n >= 48) trti[base + n - 48] = d2;           // CP
    }
    __syncthreads();

    // ---- P3: upsample x8 + RRC polyphase + carrier -> dxr (swizzled), sumsq ----
    float ss = 0.f;
    for (int a = tid; a < 656; a += 256) {
        float accr[8] = {}, acci[8] = {};
        #pragma unroll 4
        for (int d = 0; d < 16; ++d) {
            int m = a - d;
            bool ok = ((unsigned)m < 640u);
            int mc = ok ? m : 0;
            float2 tv = trti[mc];
            float vr = ok ? tv.x : 0.f;
            float vi = ok ? tv.y : 0.f;
            #pragma unroll
            for (int r = 0; r < 8; ++r) {
                float h = hl[r + 8 * d];
                accr[r] += vr * h; acci[r] += vi * h;
            }
        }
        {   // d=16, tap 128, r=0 only
            int m = a - 16;
            if ((unsigned)m < 640u) {
                float2 tv = trti[m];
                float h = hl[128];
                accr[0] += tv.x * h; acci[0] += tv.y * h;
            }
        }
        int cb = (a & 1) * 8;
        #pragma unroll
        for (int r = 0; r < 8; ++r) {
            float v = accr[r] * csl[cb + r] - acci[r] * ssl[cb + r];
            dxr[SWZ(a * 8 + r)] = v;
            ss += v * v;
        }
    }
    ss = wave_sum(ss);
    if (lane == 0) red[wv] = ss;
    __syncthreads();
    float thr = 1.2f * sqrtf((red[0] + red[1] + red[2] + red[3]) / (float)L1_);
    __syncthreads();

    // ---- P5: clip + PAPR window stats + AWGN (in place) ----
    float pmax = 0.f, psum = 0.f;
    for (int i = tid; i < L1_; i += 256) {
        float x = dxr[SWZ(i)];
        float ax = fabsf(x);
        float over = ax - thr; over = over > 0.f ? over : 0.f;
        float y = (1.f - over / (ax + 1e-8f)) * x;
        if (i >= TSTART_ && i < TSTART_ + NWIN_) { float p = y * y; psum += p; pmax = fmaxf(pmax, p); }
        dxr[SWZ(i)] = y + awgn[(size_t)b * L1_ + i];
    }
    psum = wave_sum(psum); pmax = wave_max(pmax);
    if (lane == 0) { red[wv] = psum; red2[wv] = pmax; }
    __syncthreads();
    if (tid == 0) {
        float sum = red[0] + red[1] + red[2] + red[3];
        float mx = fmaxf(fmaxf(red2[0], red2[1]), fmaxf(red2[2], red2[3]));
        float pdb = 10.f * log10f(mx / (sum / (float)NWIN_));
        papr[b] = pdb;
        out_papr[b] = pdb;
    }
    __syncthreads();     // also guarantees all P5 dxr writes visible before P6

    // ---- P6: matched RRC filter, carrier folded into gcs taps ----
    #pragma unroll
    for (int j0 = 0; j0 < 2; ++j0) {
        int j = j0 * 256 + tid;
        int s = j >> 6, n = j & 63;
        int T = s * 80 + n + 32;                         // Nf/8
        int base = 9 * T;                                // SWZ(Nf)
        int db = 0;
        float ar = 0.f, ai = 0.f;
        for (int e = 0; e < 16; ++e) {
            #pragma unroll
            for (int u = 0; u < 8; ++u) {
                int off = (u == 0) ? 0 : (u + 1);
                float v = dxr[base - off];
                float2 g = gcs[db + u];
                ar += v * g.x; ai += v * g.y;
            }
            base -= 9; db += 8;
        }
        { float v = dxr[base]; float2 g = gcs[128]; ar += v * g.x; ai += v * g.y; }
        float sr = (n & 1) ? -ar : ar;                   // odd n: taps negate
        float si = (n & 1) ? ai : -ai;                   // wil = -(sign*ai)
        wrli[j] = make_float2(sr, si);
    }
    __syncthreads();

    // ---- P7: DFT64 -> band select -> fftshift ----
    {
        int s = tid >> 5, kk = tid & 31;
        int f = sloc + kk;
        float vr = 0.f, vi = 0.f;
        int t = 0;
        for (int n = 0; n < 64; ++n) {
            float2 w = cs64[t];
            float2 d = wrli[s * 64 + n];
            vr += d.x * w.x + d.y * w.y;                 // * e^{-i ang}
            vi += d.y * w.x - d.x * w.y;
            t = (t + f) & 63;
        }
        int ksh = (kk + 16) & 31;
        frfi[s][ksh] = make_float2(vr * 0.125f, vi * 0.125f);
    }
    __syncthreads();

    // ---- P8: IDFT32 -> y5 hi/lo bf16 planes ----
    {
        int s = tid >> 5, q2 = tid & 31;
        float ur = 0.f, ui = 0.f;
        int t2 = 0;
        for (int k = 0; k < 32; ++k) {
            float2 w = cs64[2 * t2];
            float2 f = frfi[s][k];
            ur += f.x * w.x - f.y * w.y;                 // * e^{+i ang}
            ui += f.y * w.x + f.x * w.y;
            t2 = (t2 + q2) & 31;
        }
        ur *= 0.1767766952966369f; ui *= 0.1767766952966369f;
        ushort hr, lr, hi2, li2;
        split1(ur, hr, lr); split1(ui, hi2, li2);
        int idx = (s * 32 + q2) * 2;
        ushort2 hv; hv.x = hr; hv.y = hi2;
        ushort2 lv; lv.x = lr; lv.y = li2;
        *(ushort2*)&y5h[(size_t)b * 512 + idx] = hv;
        *(ushort2*)&y5l[(size_t)b * 512 + idx] = lv;
    }
}

__global__ __launch_bounds__(256) void loss_k(const float* __restrict__ papr,
        float* out_loss) {
    __shared__ float red[4];
    int tid = threadIdx.x, lane = tid & 63, wv = tid >> 6;
    float s = 0.f;
    for (int i = tid; i < 1024; i += 256) { float v = papr[i] - 8.f; s += v > 0.f ? v : 0.f; }
    s = wave_sum(s);
    if (lane == 0) red[wv] = s;
    __syncthreads();
    if (tid == 0) *out_loss = (red[0] + red[1] + red[2] + red[3]) * (1.f / 1024.f);
}

extern "C" void kernel_launch(void* const* d_in, const int* in_sizes, int n_in,
                              void* d_out, int out_size, void* d_ws, size_t ws_size,
                              hipStream_t stream) {
    const float* x    = (const float*)d_in[0];
    const float* Wenc = (const float*)d_in[1];
    const float* benc = (const float*)d_in[2];
    const float* Wdec = (const float*)d_in[3];
    const float* bdec = (const float*)d_in[4];
    const float* rrc  = (const float*)d_in[5];
    const float* awgn = (const float*)d_in[6];
    const int* sloc   = (const int*)d_in[7];
    float* out = (float*)d_out;

    char* wsb = (char*)d_ws;
    ushort* xh   = (ushort*)wsb;                     wsb += (size_t)1024 * 3072 * 2;
    ushort* xl   = (ushort*)wsb;                     wsb += (size_t)1024 * 3072 * 2;
    ushort* wt1h = (ushort*)wsb;                     wsb += (size_t)512 * 3072 * 2;
    ushort* wt1l = (ushort*)wsb;                     wsb += (size_t)512 * 3072 * 2;
    ushort* wt2h = (ushort*)wsb;                     wsb += (size_t)3072 * 512 * 2;
    ushort* wt2l = (ushort*)wsb;                     wsb += (size_t)3072 * 512 * 2;
    ushort* y5h  = (ushort*)wsb;                     wsb += (size_t)1024 * 512 * 2;
    ushort* y5l  = (ushort*)wsb;                     wsb += (size_t)1024 * 512 * 2;
    float*  z    = (float*)wsb;                      wsb += (size_t)1024 * 512 * 4;
    float*  papr = (float*)wsb;                      wsb += 1024 * 4;
    // total ws ~ 27.3 MB

    float* out_papr = out + (size_t)1024 * 3072;
    float* out_loss = out_papr + 1024;

    packA_k<<<3072, 256, 0, stream>>>(x, xh, xl);                        // 1024x3072
    packWt_k<<<dim3(8, 48), 256, 0, stream>>>(Wenc, wt1h, wt1l, 3072, 512);
    packWt_k<<<dim3(48, 8), 256, 0, stream>>>(Wdec, wt2h, wt2l, 512, 3072);
    initz_k<<<2048, 256, 0, stream>>>(z, benc);
    gemm_planes_k<16>
        <<<dim3(4, 8, 16), 256, 0, stream>>>(xh, xl, wt1h, wt1l, z, 1024, 512, 3072);
    mega_k<<<1024, 256, 0, stream>>>(z, rrc, awgn, sloc, y5h, y5l, papr, out_papr);
    loss_k<<<1, 256, 0, stream>>>(papr, out_loss);
    initout_k<<<12288, 256, 0, stream>>>(out, bdec);
    gemm_planes_k<2>
        <<<dim3(24, 8, 2), 256, 0, stream>>>(y5h, y5l, wt2h, wt2l, out, 1024, 3072, 512);
}

// Round 9
// 200.923 us; speedup vs baseline: 1.1427x; 1.1427x over previous
//
#include <hip/hip_runtime.h>
#include <hip/hip_bf16.h>
#include <math.h>

#define L1_     5248
#define LENRRC_ 129
#define TSTART_ 65
#define NWIN_   5120
#define SWZ(m) ((m) + ((m) >> 3))     // stride-8 reads -> stride-9 -> conflict-free

typedef __attribute__((ext_vector_type(8))) short s16x8;   // 8 bf16 lanes (4 VGPRs)
typedef __attribute__((ext_vector_type(4))) float f32x4;   // MFMA accumulator

// split fp32 -> hi bf16 (RNE) + lo bf16 (trunc of residual)
__device__ inline void split1(float x, ushort& h, ushort& l) {
    unsigned xb = __float_as_uint(x);
    unsigned hi = (xb + 0x7fffu + ((xb >> 16) & 1u)) & 0xffff0000u;
    h = (ushort)(hi >> 16);
    l = (ushort)(__float_as_uint(x - __uint_as_float(hi)) >> 16);
}
__device__ inline unsigned pack_pair(float x) {   // hi in high16 | lo in low16
    unsigned xb = __float_as_uint(x);
    unsigned hi = (xb + 0x7fffu + ((xb >> 16) & 1u)) & 0xffff0000u;
    float lof = x - __uint_as_float(hi);
    return hi | (__float_as_uint(lof) >> 16);
}
__device__ inline ushort bf16_rne(float x) {
    unsigned xb = __float_as_uint(x);
    return (ushort)((xb + 0x7fffu + ((xb >> 16) & 1u)) >> 16);
}

__device__ inline float wave_sum(float v) {
    #pragma unroll
    for (int m = 32; m > 0; m >>= 1) v += __shfl_xor(v, m, 64);
    return v;
}
__device__ inline float wave_max(float v) {
    #pragma unroll
    for (int m = 32; m > 0; m >>= 1) v = fmaxf(v, __shfl_xor(v, m, 64));
    return v;
}

// ---------- pack x: fp32 -> single bf16 plane ----------
__global__ __launch_bounds__(256) void packX_k(const float* __restrict__ A,
        ushort* __restrict__ Ab) {
    int i = blockIdx.x * 256 + threadIdx.x;          // x4 floats
    float4 v = ((const float4*)A)[i];
    ushort4 h;
    h.x = bf16_rne(v.x); h.y = bf16_rne(v.y);
    h.z = bf16_rne(v.z); h.w = bf16_rne(v.w);
    ((ushort4*)Ab)[i] = h;
}

// ---------- pack W1 (K x N) -> transposed single bf16 (N x K) ----------
__global__ __launch_bounds__(256) void packWt1_k(const float* __restrict__ W,
        ushort* __restrict__ T, int K, int N) {
    __shared__ ushort tile[64][70];
    const int n0 = blockIdx.x * 64, k0 = blockIdx.y * 64;
    const int t = threadIdx.x;
    const int cr = t >> 4, cc = (t & 15) * 4;
    #pragma unroll
    for (int i = 0; i < 4; ++i) {
        int kk = i * 16 + cr;
        float4 v = *(const float4*)&W[(size_t)(k0 + kk) * N + n0 + cc];
        tile[kk][cc]     = bf16_rne(v.x);
        tile[kk][cc + 1] = bf16_rne(v.y);
        tile[kk][cc + 2] = bf16_rne(v.z);
        tile[kk][cc + 3] = bf16_rne(v.w);
    }
    __syncthreads();
    #pragma unroll
    for (int i = 0; i < 4; ++i) {
        int nn = i * 16 + cr;
        ushort4 h;
        h.x = tile[cc][nn]; h.y = tile[cc + 1][nn];
        h.z = tile[cc + 2][nn]; h.w = tile[cc + 3][nn];
        *(ushort4*)&T[(size_t)(n0 + nn) * K + k0 + cc] = h;
    }
}

// ---------- pack W2 (K x N) -> transposed hi/lo split planes (N x K) ----------
__global__ __launch_bounds__(256) void packWt_k(const float* __restrict__ W,
        ushort* __restrict__ Th, ushort* __restrict__ Tl, int K, int N) {
    __shared__ unsigned tile[64][65];
    const int n0 = blockIdx.x * 64, k0 = blockIdx.y * 64;
    const int t = threadIdx.x;
    const int cr = t >> 4, cc = (t & 15) * 4;
    #pragma unroll
    for (int i = 0; i < 4; ++i) {
        int kk = i * 16 + cr;
        float4 v = *(const float4*)&W[(size_t)(k0 + kk) * N + n0 + cc];
        tile[kk][cc]     = pack_pair(v.x);
        tile[kk][cc + 1] = pack_pair(v.y);
        tile[kk][cc + 2] = pack_pair(v.z);
        tile[kk][cc + 3] = pack_pair(v.w);
    }
    __syncthreads();
    #pragma unroll
    for (int i = 0; i < 4; ++i) {
        int nn = i * 16 + cr;
        unsigned a = tile[cc][nn], b = tile[cc + 1][nn];
        unsigned c = tile[cc + 2][nn], d = tile[cc + 3][nn];
        ushort4 h, l;
        h.x = (ushort)(a >> 16); h.y = (ushort)(b >> 16);
        h.z = (ushort)(c >> 16); h.w = (ushort)(d >> 16);
        l.x = (ushort)a; l.y = (ushort)b; l.z = (ushort)c; l.w = (ushort)d;
        *(ushort4*)&Th[(size_t)(n0 + nn) * K + k0 + cc] = h;
        *(ushort4*)&Tl[(size_t)(n0 + nn) * K + k0 + cc] = l;
    }
}

// ---------- init z with bias ----------
__global__ __launch_bounds__(256) void initz_k(float* z, const float* bias) {
    int i = blockIdx.x * 256 + threadIdx.x;          // 524288 total
    z[i] = bias[i & 511];
}

// ---------- gemm1: single bf16 planes, 128x128xBK64, atomic split-K ----------
template<int SK>
__global__ __launch_bounds__(256) void gemm1_k(const ushort* __restrict__ Ab,
        const ushort* __restrict__ Bb, float* __restrict__ C, int M, int N, int K)
{
    __shared__ ushort lds[2 * 9216];    // 2 planes x 128 rows x 72 (pad) = 36 KB
    const int tid = threadIdx.x;
    const int lane = tid & 63, wave = tid >> 6;
    const int wm = (wave >> 1) * 64, wn = (wave & 1) * 64;
    const int m0 = blockIdx.y * 128, n0 = blockIdx.x * 128;
    const int kch = K / SK, kbeg = blockIdx.z * kch, kend = kbeg + kch;
    const int fm = lane & 15, q = lane >> 4;
    f32x4 acc[4][4] = {};

    for (int kt = kbeg; kt < kend; kt += 64) {
        #pragma unroll
        for (int p = 0; p < 2; ++p) {
            const ushort* src = p ? Bb : Ab;
            int r0 = p ? n0 : m0;
            #pragma unroll
            for (int i = 0; i < 4; ++i) {
                int c = i * 256 + tid;
                int row = c >> 3, k8 = (c & 7) * 8;
                uint4 v = *(const uint4*)&src[(size_t)(r0 + row) * K + kt + k8];
                *(uint4*)&lds[p * 9216 + row * 72 + k8] = v;   // ds_write_b128
            }
        }
        __syncthreads();
        #pragma unroll
        for (int ks = 0; ks < 2; ++ks) {
            s16x8 a[4], b[4];
            #pragma unroll
            for (int mf = 0; mf < 4; ++mf)
                a[mf] = *(const s16x8*)&lds[(wm + mf * 16 + fm) * 72 + ks * 32 + q * 8];
            #pragma unroll
            for (int nf = 0; nf < 4; ++nf)
                b[nf] = *(const s16x8*)&lds[9216 + (wn + nf * 16 + fm) * 72 + ks * 32 + q * 8];
            #pragma unroll
            for (int mf = 0; mf < 4; ++mf)
                #pragma unroll
                for (int nf = 0; nf < 4; ++nf)
                    acc[mf][nf] = __builtin_amdgcn_mfma_f32_16x16x32_bf16(a[mf], b[nf], acc[mf][nf], 0, 0, 0);
        }
        __syncthreads();
    }

    #pragma unroll
    for (int mf = 0; mf < 4; ++mf)
        #pragma unroll
        for (int nf = 0; nf < 4; ++nf)
            #pragma unroll
            for (int r = 0; r < 4; ++r) {
                int m = m0 + wm + mf * 16 + q * 4 + r;
                int n = n0 + wn + nf * 16 + fm;
                atomicAdd(&C[(size_t)m * N + n], acc[mf][nf][r]);
            }
}

// ---------- gemm2: split hi/lo planes, 128x128x32, direct write + bias ----------
__global__ __launch_bounds__(256) void gemm2_k(
        const ushort* __restrict__ Ah, const ushort* __restrict__ Al,
        const ushort* __restrict__ Bh, const ushort* __restrict__ Bl,
        const float* __restrict__ bias, float* __restrict__ C, int M, int N, int K)
{
    __shared__ ushort lds[4 * 5120];    // 4 planes x 128 rows x 40 (pad) = 40 KB
    const int tid = threadIdx.x;
    const int lane = tid & 63, wave = tid >> 6;
    const int wm = (wave >> 1) * 64, wn = (wave & 1) * 64;
    const int m0 = blockIdx.y * 128, n0 = blockIdx.x * 128;
    const int fm = lane & 15, q = lane >> 4;
    f32x4 acc[4][4] = {};

    const ushort* srcs[4] = {Ah, Al, Bh, Bl};
    for (int kt = 0; kt < K; kt += 32) {
        #pragma unroll
        for (int p = 0; p < 4; ++p) {
            const ushort* src = srcs[p];
            int r0 = (p < 2) ? m0 : n0;
            #pragma unroll
            for (int i = 0; i < 2; ++i) {
                int c = i * 256 + tid;
                int row = c >> 2, k8 = (c & 3) * 8;
                uint4 v = *(const uint4*)&src[(size_t)(r0 + row) * K + kt + k8];
                *(uint4*)&lds[p * 5120 + row * 40 + k8] = v;
            }
        }
        __syncthreads();
        s16x8 ah[4], al[4];
        #pragma unroll
        for (int mf = 0; mf < 4; ++mf) {
            ah[mf] = *(const s16x8*)&lds[0 * 5120 + (wm + mf * 16 + fm) * 40 + q * 8];
            al[mf] = *(const s16x8*)&lds[1 * 5120 + (wm + mf * 16 + fm) * 40 + q * 8];
        }
        #pragma unroll
        for (int nf = 0; nf < 4; ++nf) {
            s16x8 bh = *(const s16x8*)&lds[2 * 5120 + (wn + nf * 16 + fm) * 40 + q * 8];
            s16x8 bl = *(const s16x8*)&lds[3 * 5120 + (wn + nf * 16 + fm) * 40 + q * 8];
            #pragma unroll
            for (int mf = 0; mf < 4; ++mf) {
                acc[mf][nf] = __builtin_amdgcn_mfma_f32_16x16x32_bf16(ah[mf], bh, acc[mf][nf], 0, 0, 0);
                acc[mf][nf] = __builtin_amdgcn_mfma_f32_16x16x32_bf16(ah[mf], bl, acc[mf][nf], 0, 0, 0);
                acc[mf][nf] = __builtin_amdgcn_mfma_f32_16x16x32_bf16(al[mf], bh, acc[mf][nf], 0, 0, 0);
            }
        }
        __syncthreads();
    }

    #pragma unroll
    for (int mf = 0; mf < 4; ++mf)
        #pragma unroll
        for (int nf = 0; nf < 4; ++nf)
            #pragma unroll
            for (int r = 0; r < 4; ++r) {
                int m = m0 + wm + mf * 16 + q * 4 + r;
                int n = n0 + wn + nf * 16 + fm;
                C[(size_t)m * N + n] = acc[mf][nf][r] + bias[n];
            }
}

// ---------- megakernel: one block per batch row, whole signal chain in LDS ----------
__global__ __launch_bounds__(256) void mega_k(const float* __restrict__ z,
        const float* __restrict__ rrc, const float* __restrict__ awgn,
        const int* __restrict__ slocp, ushort* __restrict__ y5h, ushort* __restrict__ y5l,
        float* __restrict__ papr, float* __restrict__ out_papr)
{
    __shared__ float  zl[512];
    __shared__ float2 frfi[8][32];
    __shared__ float2 trti[640];
    __shared__ float  hl[132];
    __shared__ float  csl[16], ssl[16];
    __shared__ float2 gcs[130];
    __shared__ float  dxr[SWZ(L1_ - 1) + 1];
    __shared__ float2 wrli[512];
    __shared__ float  red[4], red2[4];

    const int b = blockIdx.x, tid = threadIdx.x;
    const int lane = tid & 63, wv = tid >> 6;
    const int sloc = *slocp;

    // ---- tables ----
    if (tid < 16) {
        float ang = 1.9634954084936207f * (float)tid;    // 2pi*5/16
        float s, c; sincosf(ang, &s, &c);
        csl[tid] = 1.4142135623730951f * c; ssl[tid] = 1.4142135623730951f * s;
    }
    for (int e = tid; e < LENRRC_; e += 256) hl[e] = rrc[e];
    float v0 = z[(size_t)b * 512 + tid];
    float v1 = z[(size_t)b * 512 + tid + 256];
    __syncthreads();

    // ---- gcs: carrier folded into RRC taps ----
    if (tid < LENRRC_) {
        int neg = (16 - (tid & 15)) & 15;                // (-d) & 15
        gcs[tid] = make_float2(hl[tid] * csl[neg], hl[tid] * ssl[neg]);
    }

    // ---- power norm (single pass: S, Q; ddof=1) ----
    {
        float S = wave_sum(v0 + v1);
        float Q = wave_sum(v0 * v0 + v1 * v1);
        if (lane == 0) { red[wv] = S; red2[wv] = Q; }
    }
    __syncthreads();
    {
        float S = red[0] + red[1] + red[2] + red[3];
        float Q = red2[0] + red2[1] + red2[2] + red2[3];
        float mean = S * (1.f / 512.f);
        float var = (Q - S * mean) * (1.f / 511.f);
        float inv = 1.f / (sqrtf(var) + 1e-8f);
        zl[tid] = (v0 - mean) * inv; zl[tid + 256] = (v1 - mean) * inv;
    }
    __syncthreads();

    // ---- P1: DFT32 (+fftshift folded), register twiddle recurrence ----
    {
        int s = tid >> 5, kk = tid & 31;
        int kk2 = (kk + 16) & 31;
        float dsn, dcs; sincosf(0.19634954084936207f * (float)kk2, &dsn, &dcs);
        float wr = 1.f, wi = 0.f;
        float sr = 0.f, si = 0.f;
        for (int q = 0; q < 32; ++q) {
            float2 c = *(const float2*)&zl[(s * 32 + q) * 2];
            sr += c.x * wr + c.y * wi;                   // * e^{-i ang}
            si += c.y * wr - c.x * wi;
            float nwr = wr * dcs - wi * dsn;
            wi = wi * dcs + wr * dsn; wr = nwr;
        }
        frfi[s][kk] = make_float2(sr * 0.1767766952966369f, si * 0.1767766952966369f);
    }
    __syncthreads();

    // ---- P2: IDFT64 + CP, register twiddle recurrence ----
    #pragma unroll
    for (int e0 = 0; e0 < 2; ++e0) {
        int e = e0 * 256 + tid;
        int s = e >> 6, n = e & 63;
        float wr, wi, dsn, dcs;
        sincosf(0.09817477042468103f * (float)((sloc * n) & 63), &wi, &wr);
        sincosf(0.09817477042468103f * (float)n, &dsn, &dcs);
        float dr = 0.f, di = 0.f;
        for (int k = 0; k < 32; ++k) {
            float2 f = frfi[s][k];
            dr += f.x * wr - f.y * wi;                   // * e^{+i ang}
            di += f.y * wr + f.x * wi;
            float nwr = wr * dcs - wi * dsn;
            wi = wi * dcs + wr * dsn; wr = nwr;
        }
        float2 d2 = make_float2(dr * 0.125f, di * 0.125f);
        int base = s * 80;
        trti[base + 16 + n] = d2;
        if (n >= 48) trti[base + n - 48] = d2;           // CP
    }
    __syncthreads();

    // ---- P3: upsample x8 + RRC polyphase + carrier -> dxr (swizzled), sumsq ----
    float ss = 0.f;
    for (int a = tid; a < 656; a += 256) {
        float accr[8] = {}, acci[8] = {};
        #pragma unroll 4
        for (int d = 0; d < 16; ++d) {
            int m = a - d;
            bool ok = ((unsigned)m < 640u);
            int mc = ok ? m : 0;
            float2 tv = trti[mc];
            float vr = ok ? tv.x : 0.f;
            float vi = ok ? tv.y : 0.f;
            #pragma unroll
            for (int r = 0; r < 8; ++r) {
                float h = hl[r + 8 * d];
                accr[r] += vr * h; acci[r] += vi * h;
            }
        }
        {   // d=16, tap 128, r=0 only
            int m = a - 16;
            if ((unsigned)m < 640u) {
                float2 tv = trti[m];
                float h = hl[128];
                accr[0] += tv.x * h; acci[0] += tv.y * h;
            }
        }
        int cb = (a & 1) * 8;
        #pragma unroll
        for (int r = 0; r < 8; ++r) {
            float v = accr[r] * csl[cb + r] - acci[r] * ssl[cb + r];
            dxr[SWZ(a * 8 + r)] = v;
            ss += v * v;
        }
    }
    ss = wave_sum(ss);
    if (lane == 0) red[wv] = ss;
    __syncthreads();
    float thr = 1.2f * sqrtf((red[0] + red[1] + red[2] + red[3]) / (float)L1_);
    __syncthreads();

    // ---- P5: clip + PAPR window stats + AWGN (in place) ----
    float pmax = 0.f, psum = 0.f;
    for (int i = tid; i < L1_; i += 256) {
        float x = dxr[SWZ(i)];
        float ax = fabsf(x);
        float over = ax - thr; over = over > 0.f ? over : 0.f;
        float y = (1.f - over / (ax + 1e-8f)) * x;
        if (i >= TSTART_ && i < TSTART_ + NWIN_) { float p = y * y; psum += p; pmax = fmaxf(pmax, p); }
        dxr[SWZ(i)] = y + awgn[(size_t)b * L1_ + i];
    }
    psum = wave_sum(psum); pmax = wave_max(pmax);
    if (lane == 0) { red[wv] = psum; red2[wv] = pmax; }
    __syncthreads();
    if (tid == 0) {
        float sum = red[0] + red[1] + red[2] + red[3];
        float mx = fmaxf(fmaxf(red2[0], red2[1]), fmaxf(red2[2], red2[3]));
        float pdb = 10.f * log10f(mx / (sum / (float)NWIN_));
        papr[b] = pdb;
        out_papr[b] = pdb;
    }
    __syncthreads();     // also guarantees all P5 dxr writes visible before P6

    // ---- P6: matched RRC filter, carrier folded into gcs taps ----
    #pragma unroll
    for (int j0 = 0; j0 < 2; ++j0) {
        int j = j0 * 256 + tid;
        int s = j >> 6, n = j & 63;
        int T = s * 80 + n + 32;                         // Nf/8
        int base = 9 * T;                                // SWZ(Nf)
        int db = 0;
        float ar = 0.f, ai = 0.f;
        for (int e = 0; e < 16; ++e) {
            #pragma unroll
            for (int u = 0; u < 8; ++u) {
                int off = (u == 0) ? 0 : (u + 1);
                float v = dxr[base - off];
                float2 g = gcs[db + u];
                ar += v * g.x; ai += v * g.y;
            }
            base -= 9; db += 8;
        }
        { float v = dxr[base]; float2 g = gcs[128]; ar += v * g.x; ai += v * g.y; }
        float sr = (n & 1) ? -ar : ar;                   // odd n: taps negate
        float si = (n & 1) ? ai : -ai;                   // wil = -(sign*ai)
        wrli[j] = make_float2(sr, si);
    }
    __syncthreads();

    // ---- P7: DFT64 -> band select -> fftshift, register twiddle recurrence ----
    {
        int s = tid >> 5, kk = tid & 31;
        int f = sloc + kk;
        float dsn, dcs; sincosf(0.09817477042468103f * (float)f, &dsn, &dcs);
        float wr = 1.f, wi = 0.f;
        float vr = 0.f, vi = 0.f;
        for (int n = 0; n < 64; ++n) {
            float2 d = wrli[s * 64 + n];
            vr += d.x * wr + d.y * wi;                   // * e^{-i ang}
            vi += d.y * wr - d.x * wi;
            float nwr = wr * dcs - wi * dsn;
            wi = wi * dcs + wr * dsn; wr = nwr;
        }
        int ksh = (kk + 16) & 31;
        frfi[s][ksh] = make_float2(vr * 0.125f, vi * 0.125f);
    }
    __syncthreads();

    // ---- P8: IDFT32 -> y5 hi/lo bf16 planes, register twiddle recurrence ----
    {
        int s = tid >> 5, q2 = tid & 31;
        float dsn, dcs; sincosf(0.19634954084936207f * (float)q2, &dsn, &dcs);
        float wr = 1.f, wi = 0.f;
        float ur = 0.f, ui = 0.f;
        for (int k = 0; k < 32; ++k) {
            float2 f = frfi[s][k];
            ur += f.x * wr - f.y * wi;                   // * e^{+i ang}
            ui += f.y * wr + f.x * wi;
            float nwr = wr * dcs - wi * dsn;
            wi = wi * dcs + wr * dsn; wr = nwr;
        }
        ur *= 0.1767766952966369f; ui *= 0.1767766952966369f;
        ushort hr, lr, hi2, li2;
        split1(ur, hr, lr); split1(ui, hi2, li2);
        int idx = (s * 32 + q2) * 2;
        ushort2 hv; hv.x = hr; hv.y = hi2;
        ushort2 lv; lv.x = lr; lv.y = li2;
        *(ushort2*)&y5h[(size_t)b * 512 + idx] = hv;
        *(ushort2*)&y5l[(size_t)b * 512 + idx] = lv;
    }
}

__global__ __launch_bounds__(256) void loss_k(const float* __restrict__ papr,
        float* out_loss) {
    __shared__ float red[4];
    int tid = threadIdx.x, lane = tid & 63, wv = tid >> 6;
    float s = 0.f;
    for (int i = tid; i < 1024; i += 256) { float v = papr[i] - 8.f; s += v > 0.f ? v : 0.f; }
    s = wave_sum(s);
    if (lane == 0) red[wv] = s;
    __syncthreads();
    if (tid == 0) *out_loss = (red[0] + red[1] + red[2] + red[3]) * (1.f / 1024.f);
}

extern "C" void kernel_launch(void* const* d_in, const int* in_sizes, int n_in,
                              void* d_out, int out_size, void* d_ws, size_t ws_size,
                              hipStream_t stream) {
    const float* x    = (const float*)d_in[0];
    const float* Wenc = (const float*)d_in[1];
    const float* benc = (const float*)d_in[2];
    const float* Wdec = (const float*)d_in[3];
    const float* bdec = (const float*)d_in[4];
    const float* rrc  = (const float*)d_in[5];
    const float* awgn = (const float*)d_in[6];
    const int* sloc   = (const int*)d_in[7];
    float* out = (float*)d_out;

    char* wsb = (char*)d_ws;
    ushort* xb   = (ushort*)wsb;                     wsb += (size_t)1024 * 3072 * 2;
    ushort* w1t  = (ushort*)wsb;                     wsb += (size_t)512 * 3072 * 2;
    ushort* w2th = (ushort*)wsb;                     wsb += (size_t)3072 * 512 * 2;
    ushort* w2tl = (ushort*)wsb;                     wsb += (size_t)3072 * 512 * 2;
    ushort* y5h  = (ushort*)wsb;                     wsb += (size_t)1024 * 512 * 2;
    ushort* y5l  = (ushort*)wsb;                     wsb += (size_t)1024 * 512 * 2;
    float*  z    = (float*)wsb;                      wsb += (size_t)1024 * 512 * 4;
    float*  papr = (float*)wsb;                      wsb += 1024 * 4;
    // total ws ~ 22 MB

    float* out_papr = out + (size_t)1024 * 3072;
    float* out_loss = out_papr + 1024;

    packX_k<<<3072, 256, 0, stream>>>(x, xb);
    packWt1_k<<<dim3(8, 48), 256, 0, stream>>>(Wenc, w1t, 3072, 512);
    packWt_k<<<dim3(48, 8), 256, 0, stream>>>(Wdec, w2th, w2tl, 512, 3072);
    initz_k<<<2048, 256, 0, stream>>>(z, benc);
    gemm1_k<8><<<dim3(4, 8, 8), 256, 0, stream>>>(xb, w1t, z, 1024, 512, 3072);
    mega_k<<<1024, 256, 0, stream>>>(z, rrc, awgn, sloc, y5h, y5l, papr, out_papr);
    loss_k<<<1, 256, 0, stream>>>(papr, out_loss);
    gemm2_k<<<dim3(24, 8, 1), 256, 0, stream>>>(y5h, y5l, w2th, w2tl, bdec, out, 1024, 3072, 512);
}

// Round 10
// 182.757 us; speedup vs baseline: 1.2562x; 1.0994x over previous
//
#include <hip/hip_runtime.h>
#include <hip/hip_bf16.h>
#include <math.h>

#define L1_     5248
#define LENRRC_ 129
#define TSTART_ 65
#define NWIN_   5120
#define SWZ(m) ((m) + ((m) >> 3))     // stride-8 reads -> stride-9 -> conflict-free

typedef __attribute__((ext_vector_type(8))) short s16x8;   // 8 bf16 lanes (4 VGPRs)
typedef __attribute__((ext_vector_type(4))) float f32x4;   // MFMA accumulator

__device__ inline ushort bf16_rne(float x) {
    unsigned xb = __float_as_uint(x);
    return (ushort)((xb + 0x7fffu + ((xb >> 16) & 1u)) >> 16);
}

__device__ inline float wave_sum(float v) {
    #pragma unroll
    for (int m = 32; m > 0; m >>= 1) v += __shfl_xor(v, m, 64);
    return v;
}
__device__ inline float wave_max(float v) {
    #pragma unroll
    for (int m = 32; m > 0; m >>= 1) v = fmaxf(v, __shfl_xor(v, m, 64));
    return v;
}

// ---------- fused pack: x->bf16 | W1^T bf16 | W2^T bf16 | z=bias ----------
__global__ __launch_bounds__(256) void pack_k(const float* __restrict__ x,
        const float* __restrict__ W1, const float* __restrict__ W2,
        const float* __restrict__ benc,
        ushort* __restrict__ xb, ushort* __restrict__ w1t, ushort* __restrict__ w2t,
        float* __restrict__ z)
{
    __shared__ ushort tile[64][70];
    const int blk = blockIdx.x, tid = threadIdx.x;
    if (blk < 3072) {                                  // pack x (1024x3072), x4 floats
        int i = blk * 256 + tid;
        float4 v = ((const float4*)x)[i];
        ushort4 h;
        h.x = bf16_rne(v.x); h.y = bf16_rne(v.y);
        h.z = bf16_rne(v.z); h.w = bf16_rne(v.w);
        ((ushort4*)xb)[i] = h;
    } else if (blk < 3840) {                           // transpose W1 / W2 into bf16
        const float* W; ushort* T; int K, N, n0, k0;
        if (blk < 3456) {
            int idx = blk - 3072;                      // grid (8,48)
            W = W1; T = w1t; K = 3072; N = 512;
            n0 = (idx & 7) * 64; k0 = (idx >> 3) * 64;
        } else {
            int idx = blk - 3456;                      // grid (48,8)
            W = W2; T = w2t; K = 512; N = 3072;
            n0 = (idx % 48) * 64; k0 = (idx / 48) * 64;
        }
        const int cr = tid >> 4, cc = (tid & 15) * 4;
        #pragma unroll
        for (int i = 0; i < 4; ++i) {
            int kk = i * 16 + cr;
            float4 v = *(const float4*)&W[(size_t)(k0 + kk) * N + n0 + cc];
            tile[kk][cc]     = bf16_rne(v.x);
            tile[kk][cc + 1] = bf16_rne(v.y);
            tile[kk][cc + 2] = bf16_rne(v.z);
            tile[kk][cc + 3] = bf16_rne(v.w);
        }
        __syncthreads();
        #pragma unroll
        for (int i = 0; i < 4; ++i) {
            int nn = i * 16 + cr;
            ushort4 h;
            h.x = tile[cc][nn]; h.y = tile[cc + 1][nn];
            h.z = tile[cc + 2][nn]; h.w = tile[cc + 3][nn];
            *(ushort4*)&T[(size_t)(n0 + nn) * K + k0 + cc] = h;
        }
    } else {                                           // init z with bias
        int i = (blk - 3840) * 256 + tid;              // 524288 total
        z[i] = benc[i & 511];
    }
}

// ---------- gemm1: single bf16, 64x128xBK64, SK=8 atomic ----------
__global__ __launch_bounds__(256) void gemm1_k(const ushort* __restrict__ Ab,
        const ushort* __restrict__ Bb, float* __restrict__ C, int M, int N, int K)
{
    __shared__ ushort Asl[64 * 72];     // 9.2 KB
    __shared__ ushort Bsl[128 * 72];    // 18.4 KB
    const int tid = threadIdx.x;
    const int lane = tid & 63, wave = tid >> 6;
    const int wm = (wave >> 1) * 32, wn = (wave & 1) * 64;
    const int m0 = blockIdx.y * 64, n0 = blockIdx.x * 128;
    const int kch = K / 8, kbeg = blockIdx.z * kch, kend = kbeg + kch;
    const int fm = lane & 15, q = lane >> 4;
    f32x4 acc[2][4] = {};

    for (int kt = kbeg; kt < kend; kt += 64) {
        #pragma unroll
        for (int i = 0; i < 2; ++i) {                  // A 64x64
            int c = i * 256 + tid;
            int row = c >> 3, k8 = (c & 7) * 8;
            *(uint4*)&Asl[row * 72 + k8] =
                *(const uint4*)&Ab[(size_t)(m0 + row) * K + kt + k8];
        }
        #pragma unroll
        for (int i = 0; i < 4; ++i) {                  // B 128x64
            int c = i * 256 + tid;
            int row = c >> 3, k8 = (c & 7) * 8;
            *(uint4*)&Bsl[row * 72 + k8] =
                *(const uint4*)&Bb[(size_t)(n0 + row) * K + kt + k8];
        }
        __syncthreads();
        #pragma unroll
        for (int ks = 0; ks < 2; ++ks) {
            s16x8 a[2], b[4];
            #pragma unroll
            for (int mf = 0; mf < 2; ++mf)
                a[mf] = *(const s16x8*)&Asl[(wm + mf * 16 + fm) * 72 + ks * 32 + q * 8];
            #pragma unroll
            for (int nf = 0; nf < 4; ++nf)
                b[nf] = *(const s16x8*)&Bsl[(wn + nf * 16 + fm) * 72 + ks * 32 + q * 8];
            #pragma unroll
            for (int mf = 0; mf < 2; ++mf)
                #pragma unroll
                for (int nf = 0; nf < 4; ++nf)
                    acc[mf][nf] = __builtin_amdgcn_mfma_f32_16x16x32_bf16(a[mf], b[nf], acc[mf][nf], 0, 0, 0);
        }
        __syncthreads();
    }

    #pragma unroll
    for (int mf = 0; mf < 2; ++mf)
        #pragma unroll
        for (int nf = 0; nf < 4; ++nf)
            #pragma unroll
            for (int r = 0; r < 4; ++r) {
                int m = m0 + wm + mf * 16 + q * 4 + r;
                int n = n0 + wn + nf * 16 + fm;
                atomicAdd(&C[(size_t)m * N + n], acc[mf][nf][r]);
            }
}

// ---------- gemm2: single bf16, 64x64xBK64, direct + bias, fused PAPR loss ----------
__global__ __launch_bounds__(256) void gemm2_k(const ushort* __restrict__ Ab,
        const ushort* __restrict__ Bb, const float* __restrict__ bias,
        const float* __restrict__ papr, float* __restrict__ C,
        float* __restrict__ out_loss, int M, int N, int K)
{
    __shared__ ushort Asl[64 * 72];
    __shared__ ushort Bsl[64 * 72];
    __shared__ float red[4];
    const int tid = threadIdx.x;
    const int lane = tid & 63, wave = tid >> 6;
    const int wm = (wave >> 1) * 32, wn = (wave & 1) * 32;
    const int m0 = blockIdx.y * 64, n0 = blockIdx.x * 64;
    const int fm = lane & 15, q = lane >> 4;
    f32x4 acc[2][2] = {};

    for (int kt = 0; kt < K; kt += 64) {
        #pragma unroll
        for (int i = 0; i < 2; ++i) {
            int c = i * 256 + tid;
            int row = c >> 3, k8 = (c & 7) * 8;
            *(uint4*)&Asl[row * 72 + k8] =
                *(const uint4*)&Ab[(size_t)(m0 + row) * K + kt + k8];
            *(uint4*)&Bsl[row * 72 + k8] =
                *(const uint4*)&Bb[(size_t)(n0 + row) * K + kt + k8];
        }
        __syncthreads();
        #pragma unroll
        for (int ks = 0; ks < 2; ++ks) {
            s16x8 a[2], b[2];
            #pragma unroll
            for (int mf = 0; mf < 2; ++mf)
                a[mf] = *(const s16x8*)&Asl[(wm + mf * 16 + fm) * 72 + ks * 32 + q * 8];
            #pragma unroll
            for (int nf = 0; nf < 2; ++nf)
                b[nf] = *(const s16x8*)&Bsl[(wn + nf * 16 + fm) * 72 + ks * 32 + q * 8];
            #pragma unroll
            for (int mf = 0; mf < 2; ++mf)
                #pragma unroll
                for (int nf = 0; nf < 2; ++nf)
                    acc[mf][nf] = __builtin_amdgcn_mfma_f32_16x16x32_bf16(a[mf], b[nf], acc[mf][nf], 0, 0, 0);
        }
        __syncthreads();
    }

    #pragma unroll
    for (int mf = 0; mf < 2; ++mf)
        #pragma unroll
        for (int nf = 0; nf < 2; ++nf)
            #pragma unroll
            for (int r = 0; r < 4; ++r) {
                int m = m0 + wm + mf * 16 + q * 4 + r;
                int n = n0 + wn + nf * 16 + fm;
                C[(size_t)m * N + n] = acc[mf][nf][r] + bias[n];
            }

    if (blockIdx.x == 0 && blockIdx.y == 0) {          // fused PAPR loss
        float s = 0.f;
        for (int i = tid; i < 1024; i += 256) { float v = papr[i] - 8.f; s += v > 0.f ? v : 0.f; }
        s = wave_sum(s);
        if (lane == 0) red[wave] = s;
        __syncthreads();
        if (tid == 0) *out_loss = (red[0] + red[1] + red[2] + red[3]) * (1.f / 1024.f);
    }
}

// ---------- megakernel: one block per batch row, whole signal chain in LDS ----------
__global__ __launch_bounds__(256) void mega_k(const float* __restrict__ z,
        const float* __restrict__ rrc, const float* __restrict__ awgn,
        const int* __restrict__ slocp, ushort* __restrict__ y5b,
        float* __restrict__ papr, float* __restrict__ out_papr)
{
    __shared__ float  zl[512];
    __shared__ float2 frfi[8][32];
    __shared__ float2 trti[640];
    __shared__ float  hl[132];
    __shared__ float  csl[16], ssl[16];
    __shared__ float2 cs64[64];
    __shared__ float2 gcs[130];
    __shared__ float  dxr[SWZ(L1_ - 1) + 1];
    __shared__ float2 wrli[512];
    __shared__ float  red[4], red2[4];

    const int b = blockIdx.x, tid = threadIdx.x;
    const int lane = tid & 63, wv = tid >> 6;
    const int sloc = *slocp;

    // ---- tables ----
    if (tid < 64) {
        float ang = 0.09817477042468103f * (float)tid;   // 2pi/64
        float s, c; sincosf(ang, &s, &c);
        cs64[tid] = make_float2(c, s);
    }
    if (tid >= 64 && tid < 80) {
        int t = tid - 64;
        float ang = 1.9634954084936207f * (float)t;      // 2pi*5/16
        float s, c; sincosf(ang, &s, &c);
        csl[t] = 1.4142135623730951f * c; ssl[t] = 1.4142135623730951f * s;
    }
    for (int e = tid; e < LENRRC_; e += 256) hl[e] = rrc[e];
    float v0 = z[(size_t)b * 512 + tid];
    float v1 = z[(size_t)b * 512 + tid + 256];
    __syncthreads();

    // ---- gcs: carrier folded into RRC taps ----
    if (tid < LENRRC_) {
        int neg = (16 - (tid & 15)) & 15;                // (-d) & 15
        gcs[tid] = make_float2(hl[tid] * csl[neg], hl[tid] * ssl[neg]);
    }

    // ---- power norm (single pass: S, Q; ddof=1) ----
    {
        float S = wave_sum(v0 + v1);
        float Q = wave_sum(v0 * v0 + v1 * v1);
        if (lane == 0) { red[wv] = S; red2[wv] = Q; }
    }
    __syncthreads();
    {
        float S = red[0] + red[1] + red[2] + red[3];
        float Q = red2[0] + red2[1] + red2[2] + red2[3];
        float mean = S * (1.f / 512.f);
        float var = (Q - S * mean) * (1.f / 511.f);
        float inv = 1.f / (sqrtf(var) + 1e-8f);
        zl[tid] = (v0 - mean) * inv; zl[tid + 256] = (v1 - mean) * inv;
    }
    __syncthreads();

    // ---- P1: DFT32 (+fftshift folded) ----
    {
        int s = tid >> 5, kk = tid & 31;
        int kk2 = (kk + 16) & 31;
        float sr = 0.f, si = 0.f;
        int t2 = 0;
        for (int q = 0; q < 32; ++q) {
            float2 w = cs64[2 * t2];
            float2 c = *(const float2*)&zl[(s * 32 + q) * 2];
            sr += c.x * w.x + c.y * w.y;                 // * e^{-i ang}
            si += c.y * w.x - c.x * w.y;
            t2 = (t2 + kk2) & 31;
        }
        frfi[s][kk] = make_float2(sr * 0.1767766952966369f, si * 0.1767766952966369f);
    }
    __syncthreads();

    // ---- P2: IDFT64 + CP ----
    #pragma unroll
    for (int e0 = 0; e0 < 2; ++e0) {
        int e = e0 * 256 + tid;
        int s = e >> 6, n = e & 63;
        float dr = 0.f, di = 0.f;
        int t = (sloc * n) & 63;
        for (int k = 0; k < 32; ++k) {
            float2 w = cs64[t];
            float2 f = frfi[s][k];
            dr += f.x * w.x - f.y * w.y;                 // * e^{+i ang}
            di += f.y * w.x + f.x * w.y;
            t = (t + n) & 63;
        }
        float2 d2 = make_float2(dr * 0.125f, di * 0.125f);
        int base = s * 80;
        trti[base + 16 + n] = d2;
        if (n >= 48) trti[base + n - 48] = d2;           // CP
    }
    __syncthreads();

    // ---- P3: upsample x8 + RRC polyphase + carrier -> dxr (swizzled), sumsq ----
    float ss = 0.f;
    for (int a = tid; a < 656; a += 256) {
        float accr[8] = {}, acci[8] = {};
        #pragma unroll 4
        for (int d = 0; d < 16; ++d) {
            int m = a - d;
            bool ok = ((unsigned)m < 640u);
            int mc = ok ? m : 0;
            float2 tv = trti[mc];
            float vr = ok ? tv.x : 0.f;
            float vi = ok ? tv.y : 0.f;
            #pragma unroll
            for (int r = 0; r < 8; ++r) {
                float h = hl[r + 8 * d];
                accr[r] += vr * h; acci[r] += vi * h;
            }
        }
        {   // d=16, tap 128, r=0 only
            int m = a - 16;
            if ((unsigned)m < 640u) {
                float2 tv = trti[m];
                float h = hl[128];
                accr[0] += tv.x * h; acci[0] += tv.y * h;
            }
        }
        int cb = (a & 1) * 8;
        #pragma unroll
        for (int r = 0; r < 8; ++r) {
            float v = accr[r] * csl[cb + r] - acci[r] * ssl[cb + r];
            dxr[SWZ(a * 8 + r)] = v;
            ss += v * v;
        }
    }
    ss = wave_sum(ss);
    if (lane == 0) red[wv] = ss;
    __syncthreads();
    float thr = 1.2f * sqrtf((red[0] + red[1] + red[2] + red[3]) / (float)L1_);
    __syncthreads();

    // ---- P5: clip + PAPR window stats + AWGN (in place) ----
    float pmax = 0.f, psum = 0.f;
    for (int i = tid; i < L1_; i += 256) {
        float x = dxr[SWZ(i)];
        float ax = fabsf(x);
        float over = ax - thr; over = over > 0.f ? over : 0.f;
        float y = (1.f - over / (ax + 1e-8f)) * x;
        if (i >= TSTART_ && i < TSTART_ + NWIN_) { float p = y * y; psum += p; pmax = fmaxf(pmax, p); }
        dxr[SWZ(i)] = y + awgn[(size_t)b * L1_ + i];
    }
    psum = wave_sum(psum); pmax = wave_max(pmax);
    if (lane == 0) { red[wv] = psum; red2[wv] = pmax; }
    __syncthreads();
    if (tid == 0) {
        float sum = red[0] + red[1] + red[2] + red[3];
        float mx = fmaxf(fmaxf(red2[0], red2[1]), fmaxf(red2[2], red2[3]));
        float pdb = 10.f * log10f(mx / (sum / (float)NWIN_));
        papr[b] = pdb;
        out_papr[b] = pdb;
    }
    __syncthreads();     // also guarantees all P5 dxr writes visible before P6

    // ---- P6: matched RRC filter, carrier folded into gcs taps ----
    #pragma unroll
    for (int j0 = 0; j0 < 2; ++j0) {
        int j = j0 * 256 + tid;
        int s = j >> 6, n = j & 63;
        int T = s * 80 + n + 32;                         // Nf/8
        int base = 9 * T;                                // SWZ(Nf)
        int db = 0;
        float ar = 0.f, ai = 0.f;
        for (int e = 0; e < 16; ++e) {
            #pragma unroll
            for (int u = 0; u < 8; ++u) {
                int off = (u == 0) ? 0 : (u + 1);
                float v = dxr[base - off];
                float2 g = gcs[db + u];
                ar += v * g.x; ai += v * g.y;
            }
            base -= 9; db += 8;
        }
        { float v = dxr[base]; float2 g = gcs[128]; ar += v * g.x; ai += v * g.y; }
        float sr = (n & 1) ? -ar : ar;                   // odd n: taps negate
        float si = (n & 1) ? ai : -ai;                   // wil = -(sign*ai)
        wrli[j] = make_float2(sr, si);
    }
    __syncthreads();

    // ---- P7: DFT64 -> band select -> fftshift ----
    {
        int s = tid >> 5, kk = tid & 31;
        int f = sloc + kk;
        float vr = 0.f, vi = 0.f;
        int t = 0;
        for (int n = 0; n < 64; ++n) {
            float2 w = cs64[t];
            float2 d = wrli[s * 64 + n];
            vr += d.x * w.x + d.y * w.y;                 // * e^{-i ang}
            vi += d.y * w.x - d.x * w.y;
            t = (t + f) & 63;
        }
        int ksh = (kk + 16) & 31;
        frfi[s][ksh] = make_float2(vr * 0.125f, vi * 0.125f);
    }
    __syncthreads();

    // ---- P8: IDFT32 -> y5 single bf16 plane ----
    {
        int s = tid >> 5, q2 = tid & 31;
        float ur = 0.f, ui = 0.f;
        int t2 = 0;
        for (int k = 0; k < 32; ++k) {
            float2 w = cs64[2 * t2];
            float2 f = frfi[s][k];
            ur += f.x * w.x - f.y * w.y;                 // * e^{+i ang}
            ui += f.y * w.x + f.x * w.y;
            t2 = (t2 + q2) & 31;
        }
        ur *= 0.1767766952966369f; ui *= 0.1767766952966369f;
        ushort2 hv; hv.x = bf16_rne(ur); hv.y = bf16_rne(ui);
        *(ushort2*)&y5b[(size_t)b * 512 + (s * 32 + q2) * 2] = hv;
    }
}

extern "C" void kernel_launch(void* const* d_in, const int* in_sizes, int n_in,
                              void* d_out, int out_size, void* d_ws, size_t ws_size,
                              hipStream_t stream) {
    const float* x    = (const float*)d_in[0];
    const float* Wenc = (const float*)d_in[1];
    const float* benc = (const float*)d_in[2];
    const float* Wdec = (const float*)d_in[3];
    const float* bdec = (const float*)d_in[4];
    const float* rrc  = (const float*)d_in[5];
    const float* awgn = (const float*)d_in[6];
    const int* sloc   = (const int*)d_in[7];
    float* out = (float*)d_out;

    char* wsb = (char*)d_ws;
    ushort* xb   = (ushort*)wsb;                     wsb += (size_t)1024 * 3072 * 2;
    ushort* w1t  = (ushort*)wsb;                     wsb += (size_t)512 * 3072 * 2;
    ushort* w2t  = (ushort*)wsb;                     wsb += (size_t)3072 * 512 * 2;
    ushort* y5b  = (ushort*)wsb;                     wsb += (size_t)1024 * 512 * 2;
    float*  z    = (float*)wsb;                      wsb += (size_t)1024 * 512 * 4;
    float*  papr = (float*)wsb;                      wsb += 1024 * 4;
    // total ws ~ 15.8 MB

    float* out_papr = out + (size_t)1024 * 3072;
    float* out_loss = out_papr + 1024;

    pack_k<<<5888, 256, 0, stream>>>(x, Wenc, Wdec, benc, xb, w1t, w2t, z);
    gemm1_k<<<dim3(4, 16, 8), 256, 0, stream>>>(xb, w1t, z, 1024, 512, 3072);
    mega_k<<<1024, 256, 0, stream>>>(z, rrc, awgn, sloc, y5b, papr, out_papr);
    gemm2_k<<<dim3(48, 16, 1), 256, 0, stream>>>(y5b, w2t, bdec, papr, out, out_loss, 1024, 3072, 512);
}